// Round 6
// baseline (284.797 us; speedup 1.0000x reference)
//
#include <hip/hip_runtime.h>
#include <hip/hip_bf16.h>
#include <hip/hip_fp16.h>
#include <cstdint>
#include <cstddef>

#define NB 8
#define TT 1024
#define DD 512
#define HH 8
#define DHD 64

using bf16x8 = __attribute__((ext_vector_type(8))) short;
using f32x4  = __attribute__((ext_vector_type(4))) float;

#define MFMA(a, b, c) __builtin_amdgcn_mfma_f32_16x16x32_bf16((a), (b), (c), 0, 0, 0)

__device__ __forceinline__ short f2bf(float f) {
  union { float f; uint32_t u; } x; x.f = f;
  uint32_t r = x.u + 0x7fffu + ((x.u >> 16) & 1u);
  return (short)(r >> 16);
}

// pack two floats into two bf16 (round-nearest-even) in one u32
__device__ __forceinline__ uint32_t pkbf(float a, float b) {
  union { float f; uint32_t u; } x, y; x.f = a; y.f = b;
  uint32_t ra = x.u + 0x7fffu + ((x.u >> 16) & 1u);
  uint32_t rb = y.u + 0x7fffu + ((y.u >> 16) & 1u);
  return (ra >> 16) | (rb & 0xffff0000u);
}

// ---------------- weight transpose + f32->bf16 ----------------
__global__ __launch_bounds__(256) void kt_transpose(
    const float* __restrict__ W0, const float* __restrict__ W1,
    const float* __restrict__ W2, const float* __restrict__ W3,
    short* __restrict__ WT)
{
  __shared__ float tile[32][33];
  int z = blockIdx.z;
  const float* W = (z == 0) ? W0 : (z == 1) ? W1 : (z == 2) ? W2 : W3;
  short* out = WT + (size_t)z * DD * DD;
  int tx = threadIdx.x, ty = threadIdx.y;  // (32, 8)
  int bx = blockIdx.x * 32, by = blockIdx.y * 32;
#pragma unroll
  for (int kq = 0; kq < 4; ++kq)
    tile[ty + kq * 8][tx] = W[(size_t)(by + ty + kq * 8) * DD + bx + tx];
  __syncthreads();
#pragma unroll
  for (int kq = 0; kq < 4; ++kq)
    out[(size_t)(bx + ty + kq * 8) * DD + by + tx] = f2bf(tile[tx][ty + kq * 8]);
}

// ---------------- QKV projection GEMM ----------------
// z: 0=Q (scaled by 1/8, layout [N,H,T,64]), 1=K ([N,H,T,64]), 2=V ([N,H,64,T])
__global__ __launch_bounds__(256) void kt_proj(
    const float* __restrict__ Xq, const float* __restrict__ Xk, const float* __restrict__ Xv,
    const short* __restrict__ WTall,
    const float* __restrict__ bq, const float* __restrict__ bk, const float* __restrict__ bv,
    short* __restrict__ qb, short* __restrict__ kb, short* __restrict__ vT)
{
  int z = blockIdx.z;
  const float* X    = (z == 0) ? Xq : (z == 1) ? Xk : Xv;
  const short* WT   = WTall + (size_t)z * DD * DD;
  const float* bias = (z == 0) ? bq : (z == 1) ? bk : bv;
  short* out        = (z == 0) ? qb : (z == 1) ? kb : vT;

  __shared__ alignas(16) short As[64][40];
  __shared__ alignas(16) short Bs[64][40];
  int tid = threadIdx.x;
  int w = tid >> 6, lane = tid & 63, g = lane >> 4, c16 = lane & 15;
  int m0 = blockIdx.x * 64, c0 = blockIdx.y * 64;
  int srow = tid >> 2, skg = (tid & 3) * 8;
  f32x4 acc[4] = {};

  for (int kk = 0; kk < DD; kk += 32) {
    const float* ap = X + (size_t)(m0 + srow) * DD + kk + skg;
    float4 a0 = *(const float4*)ap;
    float4 a1 = *(const float4*)(ap + 4);
    bf16x8 av;
    av[0] = f2bf(a0.x); av[1] = f2bf(a0.y); av[2] = f2bf(a0.z); av[3] = f2bf(a0.w);
    av[4] = f2bf(a1.x); av[5] = f2bf(a1.y); av[6] = f2bf(a1.z); av[7] = f2bf(a1.w);
    *(bf16x8*)&As[srow][skg] = av;
    *(bf16x8*)&Bs[srow][skg] = *(const bf16x8*)(WT + (size_t)(c0 + srow) * DD + kk + skg);
    __syncthreads();
    bf16x8 af = *(const bf16x8*)&As[w * 16 + c16][g * 8];
#pragma unroll
    for (int ct = 0; ct < 4; ++ct) {
      bf16x8 bfv = *(const bf16x8*)&Bs[ct * 16 + c16][g * 8];
      acc[ct] = MFMA(af, bfv, acc[ct]);
    }
    __syncthreads();
  }

#pragma unroll
  for (int ct = 0; ct < 4; ++ct) {
    int c = c0 + ct * 16 + c16;
    float bv_ = bias[c];
    int hh = c >> 6, dh = c & 63;
#pragma unroll
    for (int r = 0; r < 4; ++r) {
      int m = m0 + w * 16 + g * 4 + r;
      int n = m >> 10, t = m & 1023;
      float val = acc[ct][r] + bv_;
      if (z == 0) val *= 0.125f;  // fold score scaling into q
      size_t addr = (z < 2)
          ? ((((size_t)n * HH + hh) * TT + t) * DHD + dh)     // q,k: [N,H,T,64]
          : ((((size_t)n * HH + hh) * DHD + dh) * TT + t);    // v : [N,H,64,T]
      out[addr] = f2bf(val);
    }
  }
}

// ---------------- output projection GEMM ----------------
__global__ __launch_bounds__(256) void kt_outproj(
    const short* __restrict__ A, const short* __restrict__ WT,
    const float* __restrict__ bias, float* __restrict__ out)
{
  __shared__ alignas(16) short As[64][40];
  __shared__ alignas(16) short Bs[64][40];
  int tid = threadIdx.x;
  int w = tid >> 6, lane = tid & 63, g = lane >> 4, c16 = lane & 15;
  int m0 = blockIdx.x * 64, c0 = blockIdx.y * 64;
  int srow = tid >> 2, skg = (tid & 3) * 8;
  f32x4 acc[4] = {};

  for (int kk = 0; kk < DD; kk += 32) {
    *(bf16x8*)&As[srow][skg] = *(const bf16x8*)(A + (size_t)(m0 + srow) * DD + kk + skg);
    *(bf16x8*)&Bs[srow][skg] = *(const bf16x8*)(WT + (size_t)(c0 + srow) * DD + kk + skg);
    __syncthreads();
    bf16x8 af = *(const bf16x8*)&As[w * 16 + c16][g * 8];
#pragma unroll
    for (int ct = 0; ct < 4; ++ct) {
      bf16x8 bfv = *(const bf16x8*)&Bs[ct * 16 + c16][g * 8];
      acc[ct] = MFMA(af, bfv, acc[ct]);
    }
    __syncthreads();
  }

#pragma unroll
  for (int ct = 0; ct < 4; ++ct) {
    int c = c0 + ct * 16 + c16;
    float bv_ = bias[c];
#pragma unroll
    for (int r = 0; r < 4; ++r) {
      int m = m0 + w * 16 + g * 4 + r;
      out[(size_t)m * DD + c] = acc[ct][r] + bv_;
    }
  }
}

// ---------------- fused attention, v7 ----------------
// v6 macrostructure + SOFTWARE PIPELINE across the h-loop:
//  - K/Q of head h+1 prefetched into loop-carried registers right after head
//    h's QK^T consumes the current fragments (latency hidden under softmax +
//    2 barriers + PV of head h).
//  - V[h] issued immediately after QK^T, consumed by PV ~800 cyc later.
//  - Each load cluster pinned with sched_barrier(0) so the backend scheduler
//    cannot sink the loads to their uses (v6's failure: VGPR stayed 108).
__global__ __launch_bounds__(512) void kt_attn(
    const short* __restrict__ qbuf, const short* __restrict__ kbuf, const short* __restrict__ vT,
    const float* __restrict__ segms, const int* __restrict__ mask,
    short* __restrict__ attn, float* __restrict__ pmean)
{
  int bx = blockIdx.x;
  int n = bx & 7, qt = bx >> 3;          // XCD-local batch
  int tid = threadIdx.x, w = tid >> 6, lane = tid & 63, g = lane >> 4, c16 = lane & 15;
  int kw = w * 128;

  // per-wave union region: pbuf short[16][136] (4352 B) | outred float[16][66] (4224 B)
  __shared__ alignas(16) char uni[8][4352];
  __shared__ alignas(16) float red_mT[16][8];
  __shared__ alignas(16) float red_sT[16][8];
  short (*pbuf)[136] = (short (*)[136])uni[w];
  float (*outw)[66]  = (float (*)[66])uni[w];

  // ---- hoist mask bits + segms (fp16 packed); h-invariant; vectorized ----
  // lane owns q-row (qt*16 + c16), k-cols kw + ct*16 + g*4 + {0..3}
  unsigned mm = 0u;
  __half2 sgp[8][2];
  float pm[8][4];
  uint32_t rowbase = ((uint32_t)(n * TT) + qt * 16 + c16) * TT + kw + g * 4;
#pragma unroll
  for (int ct = 0; ct < 8; ++ct) {
    int4   mv = *(const int4*)  &mask [rowbase + ct * 16];
    float4 sg = *(const float4*)&segms[rowbase + ct * 16];
    if (mv.x) mm |= 1u << (ct * 4 + 0);
    if (mv.y) mm |= 1u << (ct * 4 + 1);
    if (mv.z) mm |= 1u << (ct * 4 + 2);
    if (mv.w) mm |= 1u << (ct * 4 + 3);
    sgp[ct][0] = __floats2half2_rn(sg.x, sg.y);
    sgp[ct][1] = __floats2half2_rn(sg.z, sg.w);
    pm[ct][0] = 0.f; pm[ct][1] = 0.f; pm[ct][2] = 0.f; pm[ct][3] = 0.f;
  }

  // ---- prologue: prefetch K,Q of first head into loop-carried regs ----
  bf16x8 kf0[8], kf1[8], aq0, aq1;
  {
    int h0 = qt & 7;
    const short* qp = qbuf + ((((size_t)n * HH + h0) * TT) + qt * 16) * DHD;
    const short* kp = kbuf + (((size_t)n * HH + h0) * TT) * DHD;
    aq0 = *(const bf16x8*)(qp + c16 * DHD + g * 8);
    aq1 = *(const bf16x8*)(qp + c16 * DHD + g * 8 + 32);
#pragma unroll
    for (int ct = 0; ct < 8; ++ct) {
      const short* kpp = kp + (size_t)(kw + ct * 16 + c16) * DHD + g * 8;
      kf0[ct] = *(const bf16x8*)kpp;
      kf1[ct] = *(const bf16x8*)(kpp + 32);
    }
  }
  __builtin_amdgcn_sched_barrier(0);

  for (int hh = 0; hh < HH; ++hh) {
    int h  = (hh + qt) & 7;       // stagger heads across blocks
    int hn = (hh + 1 + qt) & 7;   // next head (prefetch target)
    const short* vp = vT + (((size_t)n * HH + h) * DHD) * TT;

    // ---- swapped QK^T from prefetched regs: sc[ct][r] = S(q=c16, k=kw+ct*16+g*4+r) ----
    f32x4 sc[8];
    __builtin_amdgcn_s_setprio(1);
#pragma unroll
    for (int ct = 0; ct < 8; ++ct) {
      f32x4 a = {};
      a = MFMA(kf0[ct], aq0, a);
      a = MFMA(kf1[ct], aq1, a);
      sc[ct] = a;
    }
    __builtin_amdgcn_s_setprio(0);
    __builtin_amdgcn_sched_barrier(0);

    // ---- issue ALL 16 V[h] fragment loads (consumed by PV ~800 cyc later) ----
    bf16x8 vf[16];
#pragma unroll
    for (int ks = 0; ks < 4; ++ks)
#pragma unroll
      for (int ct = 0; ct < 4; ++ct)
        vf[ks * 4 + ct] = *(const bf16x8*)(vp + (size_t)(ct * 16 + c16) * TT + kw + ks * 32 + g * 8);
    __builtin_amdgcn_sched_barrier(0);

    // ---- issue K,Q prefetch for head h+1 (regs dead after QK^T above) ----
    {
      const short* qpn = qbuf + ((((size_t)n * HH + hn) * TT) + qt * 16) * DHD;
      const short* kpn = kbuf + (((size_t)n * HH + hn) * TT) * DHD;
      aq0 = *(const bf16x8*)(qpn + c16 * DHD + g * 8);
      aq1 = *(const bf16x8*)(qpn + c16 * DHD + g * 8 + 32);
#pragma unroll
      for (int ct = 0; ct < 8; ++ct) {
        const short* kpp = kpn + (size_t)(kw + ct * 16 + c16) * DHD + g * 8;
        kf0[ct] = *(const bf16x8*)kpp;
        kf1[ct] = *(const bf16x8*)(kpp + 32);
      }
    }
    __builtin_amdgcn_sched_barrier(0);

    // ---- mask + in-lane row max + 2 shuffles ----
    float mx = -3e38f;
#pragma unroll
    for (int ct = 0; ct < 8; ++ct)
#pragma unroll
      for (int r = 0; r < 4; ++r) {
        float s = ((mm >> (ct * 4 + r)) & 1u) ? sc[ct][r] : -1e9f;
        sc[ct][r] = s;
        mx = fmaxf(mx, s);
      }
    mx = fmaxf(mx, __shfl_xor(mx, 16));
    mx = fmaxf(mx, __shfl_xor(mx, 32));

    // ---- exp with wave-local max (p<=1 safe) + in-lane sum + 2 shuffles ----
    float sm = 0.f;
#pragma unroll
    for (int ct = 0; ct < 8; ++ct)
#pragma unroll
      for (int r = 0; r < 4; ++r) {
        float p = __expf(sc[ct][r] - mx);
        sc[ct][r] = p;
        sm += p;
      }
    sm += __shfl_xor(sm, 16);
    sm += __shfl_xor(sm, 32);
    if (lane < 16) {
      red_mT[c16][w] = mx;
      red_sT[c16][w] = sm;
    }
    __syncthreads();  // barrier A: (m,S) ready; fences prev head's outw reads vs pbuf writes

    // ---- combine: scale_w = exp(m_w - m*) / Z ----
    f32x4 vm0 = *(const f32x4*)&red_mT[c16][0];
    f32x4 vm1 = *(const f32x4*)&red_mT[c16][4];
    f32x4 vs0 = *(const f32x4*)&red_sT[c16][0];
    f32x4 vs1 = *(const f32x4*)&red_sT[c16][4];
    float ms = fmaxf(fmaxf(fmaxf(vm0[0], vm0[1]), fmaxf(vm0[2], vm0[3])),
                     fmaxf(fmaxf(vm1[0], vm1[1]), fmaxf(vm1[2], vm1[3])));
    float Z = vs0[0] * __expf(vm0[0] - ms) + vs0[1] * __expf(vm0[1] - ms)
            + vs0[2] * __expf(vm0[2] - ms) + vs0[3] * __expf(vm0[3] - ms)
            + vs1[0] * __expf(vm1[0] - ms) + vs1[1] * __expf(vm1[1] - ms)
            + vs1[2] * __expf(vm1[2] - ms) + vs1[3] * __expf(vm1[3] - ms);
    float scl = __expf(mx - ms) / Z;

    // ---- probs = p*scale*segms ; accumulate pmean ; stash packed b64 ----
#pragma unroll
    for (int ct = 0; ct < 8; ++ct) {
      float2 s01 = __half22float2(sgp[ct][0]);
      float2 s23 = __half22float2(sgp[ct][1]);
      float p0 = sc[ct][0] * scl * s01.x;
      float p1 = sc[ct][1] * scl * s01.y;
      float p2 = sc[ct][2] * scl * s23.x;
      float p3 = sc[ct][3] * scl * s23.y;
      pm[ct][0] += p0; pm[ct][1] += p1; pm[ct][2] += p2; pm[ct][3] += p3;
      uint2 pk; pk.x = pkbf(p0, p1); pk.y = pkbf(p2, p3);
      *(uint2*)&pbuf[c16][ct * 16 + g * 4] = pk;
    }
    // no barrier: pbuf slice is wave-private (same-wave ds ordering)

    // ---- PV over this wave's 128-k slice (V staged in registers) ----
    f32x4 oa[4] = {};
    __builtin_amdgcn_s_setprio(1);
#pragma unroll
    for (int ks = 0; ks < 4; ++ks) {
      bf16x8 pa = *(const bf16x8*)&pbuf[c16][ks * 32 + g * 8];
#pragma unroll
      for (int ct = 0; ct < 4; ++ct)
        oa[ct] = MFMA(pa, vf[ks * 4 + ct], oa[ct]);
    }
    __builtin_amdgcn_s_setprio(0);

    // overwrite own (dead) pbuf region with PV partials — wave-private
#pragma unroll
    for (int ct = 0; ct < 4; ++ct)
#pragma unroll
      for (int r = 0; r < 4; ++r)
        outw[g * 4 + r][ct * 16 + c16] = oa[ct][r];
    __syncthreads();  // barrier C: all partials ready

    // ---- cross-wave reduce (8 partials) + write attn[n][t][h*64+d] ----
    {
      int q = tid >> 5, dg = (tid & 31) * 2;
      float v0 = 0.f, v1 = 0.f;
#pragma unroll
      for (int wi = 0; wi < 8; ++wi) {
        float2 rd = *(const float2*)((const float*)uni[wi] + q * 66 + dg);
        v0 += rd.x;
        v1 += rd.y;
      }
      ushort2 st;
      st.x = (unsigned short)f2bf(v0);
      st.y = (unsigned short)f2bf(v1);
      *(ushort2*)(attn + ((size_t)(n * TT) + qt * 16 + q) * DD + h * DHD + dg) = st;
    }
    // next head's pbuf writes are fenced by barrier A of that head
  }

  // ---- write probs mean (1/H), vectorized float4 ----
#pragma unroll
  for (int ct = 0; ct < 8; ++ct) {
    float4 o;
    o.x = pm[ct][0] * 0.125f; o.y = pm[ct][1] * 0.125f;
    o.z = pm[ct][2] * 0.125f; o.w = pm[ct][3] * 0.125f;
    *(float4*)&pmean[rowbase + ct * 16] = o;
  }
}

extern "C" void kernel_launch(void* const* d_in, const int* in_sizes, int n_in,
                              void* d_out, int out_size, void* d_ws, size_t ws_size,
                              hipStream_t stream) {
  const float* query = (const float*)d_in[0];
  const float* key_  = (const float*)d_in[1];
  const float* value = (const float*)d_in[2];
  const float* segms = (const float*)d_in[3];
  const int*   mask  = (const int*)d_in[4];
  const float* Wq = (const float*)d_in[5];
  const float* bq = (const float*)d_in[6];
  const float* Wk = (const float*)d_in[7];
  const float* bk = (const float*)d_in[8];
  const float* Wv = (const float*)d_in[9];
  const float* bv = (const float*)d_in[10];
  const float* Wo = (const float*)d_in[11];
  const float* bo = (const float*)d_in[12];

  char* ws = (char*)d_ws;
  short* WT   = (short*)(ws);                        // 4 x 512x512 bf16 = 2 MB
  short* qb   = (short*)(ws + ((size_t)2  << 20));   // [N,H,T,64] bf16 = 8 MB
  short* kb   = (short*)(ws + ((size_t)10 << 20));   // [N,H,T,64] bf16 = 8 MB
  short* vT   = (short*)(ws + ((size_t)18 << 20));   // [N,H,64,T] bf16 = 8 MB
  short* attn = (short*)(ws + ((size_t)26 << 20));   // [N,T,D]   bf16 = 8 MB
  float* outp  = (float*)d_out;
  float* pmean = outp + (size_t)NB * TT * DD;

  kt_transpose<<<dim3(16, 16, 4), dim3(32, 8), 0, stream>>>(Wq, Wk, Wv, Wo, WT);
  kt_proj<<<dim3(128, 8, 3), 256, 0, stream>>>(query, key_, value, WT, bq, bk, bv, qb, kb, vT);
  kt_attn<<<dim3(512), dim3(512), 0, stream>>>(qb, kb, vT, segms, mask, attn, pmean);
  kt_outproj<<<dim3(128, 8), 256, 0, stream>>>(attn, WT + (size_t)3 * DD * DD, bo, outp);
}

// Round 7
// 186.123 us; speedup vs baseline: 1.5302x; 1.5302x over previous
//
#include <hip/hip_runtime.h>
#include <hip/hip_bf16.h>
#include <hip/hip_fp16.h>
#include <cstdint>
#include <cstddef>

#define NB 8
#define TT 1024
#define DD 512
#define HH 8
#define DHD 64

using bf16x8 = __attribute__((ext_vector_type(8))) short;
using f32x4  = __attribute__((ext_vector_type(4))) float;
using s16x4  = __attribute__((ext_vector_type(4))) short;

#define MFMA(a, b, c) __builtin_amdgcn_mfma_f32_16x16x32_bf16((a), (b), (c), 0, 0, 0)

__device__ __forceinline__ short f2bf(float f) {
  union { float f; uint32_t u; } x; x.f = f;
  uint32_t r = x.u + 0x7fffu + ((x.u >> 16) & 1u);
  return (short)(r >> 16);
}

// pack two floats into two bf16 (round-nearest-even) in one u32
__device__ __forceinline__ uint32_t pkbf(float a, float b) {
  union { float f; uint32_t u; } x, y; x.f = a; y.f = b;
  uint32_t ra = x.u + 0x7fffu + ((x.u >> 16) & 1u);
  uint32_t rb = y.u + 0x7fffu + ((y.u >> 16) & 1u);
  return (ra >> 16) | (rb & 0xffff0000u);
}

// ---------------- weight transpose + f32->bf16 ----------------
__global__ __launch_bounds__(256) void kt_transpose(
    const float* __restrict__ W0, const float* __restrict__ W1,
    const float* __restrict__ W2, const float* __restrict__ W3,
    short* __restrict__ WT)
{
  __shared__ float tile[32][33];
  int z = blockIdx.z;
  const float* W = (z == 0) ? W0 : (z == 1) ? W1 : (z == 2) ? W2 : W3;
  short* out = WT + (size_t)z * DD * DD;
  int tx = threadIdx.x, ty = threadIdx.y;  // (32, 8)
  int bx = blockIdx.x * 32, by = blockIdx.y * 32;
#pragma unroll
  for (int kq = 0; kq < 4; ++kq)
    tile[ty + kq * 8][tx] = W[(size_t)(by + ty + kq * 8) * DD + bx + tx];
  __syncthreads();
#pragma unroll
  for (int kq = 0; kq < 4; ++kq)
    out[(size_t)(bx + ty + kq * 8) * DD + by + tx] = f2bf(tile[tx][ty + kq * 8]);
}

// ---------------- QKV projection GEMM ----------------
// z: 0=Q (scaled by 1/8, layout [N,H,T,64]), 1=K ([N,H,T,64]), 2=V ([N,H,64,T])
__global__ __launch_bounds__(256) void kt_proj(
    const float* __restrict__ Xq, const float* __restrict__ Xk, const float* __restrict__ Xv,
    const short* __restrict__ WTall,
    const float* __restrict__ bq, const float* __restrict__ bk, const float* __restrict__ bv,
    short* __restrict__ qb, short* __restrict__ kb, short* __restrict__ vT)
{
  int z = blockIdx.z;
  const float* X    = (z == 0) ? Xq : (z == 1) ? Xk : Xv;
  const short* WT   = WTall + (size_t)z * DD * DD;
  const float* bias = (z == 0) ? bq : (z == 1) ? bk : bv;
  short* out        = (z == 0) ? qb : (z == 1) ? kb : vT;

  __shared__ alignas(16) short As[64][40];
  __shared__ alignas(16) short Bs[64][40];
  int tid = threadIdx.x;
  int w = tid >> 6, lane = tid & 63, g = lane >> 4, c16 = lane & 15;
  int m0 = blockIdx.x * 64, c0 = blockIdx.y * 64;
  int srow = tid >> 2, skg = (tid & 3) * 8;
  f32x4 acc[4] = {};

  for (int kk = 0; kk < DD; kk += 32) {
    const float* ap = X + (size_t)(m0 + srow) * DD + kk + skg;
    float4 a0 = *(const float4*)ap;
    float4 a1 = *(const float4*)(ap + 4);
    bf16x8 av;
    av[0] = f2bf(a0.x); av[1] = f2bf(a0.y); av[2] = f2bf(a0.z); av[3] = f2bf(a0.w);
    av[4] = f2bf(a1.x); av[5] = f2bf(a1.y); av[6] = f2bf(a1.z); av[7] = f2bf(a1.w);
    *(bf16x8*)&As[srow][skg] = av;
    *(bf16x8*)&Bs[srow][skg] = *(const bf16x8*)(WT + (size_t)(c0 + srow) * DD + kk + skg);
    __syncthreads();
    bf16x8 af = *(const bf16x8*)&As[w * 16 + c16][g * 8];
#pragma unroll
    for (int ct = 0; ct < 4; ++ct) {
      bf16x8 bfv = *(const bf16x8*)&Bs[ct * 16 + c16][g * 8];
      acc[ct] = MFMA(af, bfv, acc[ct]);
    }
    __syncthreads();
  }

#pragma unroll
  for (int ct = 0; ct < 4; ++ct) {
    int c = c0 + ct * 16 + c16;
    float bv_ = bias[c];
    int hh = c >> 6, dh = c & 63;
#pragma unroll
    for (int r = 0; r < 4; ++r) {
      int m = m0 + w * 16 + g * 4 + r;
      int n = m >> 10, t = m & 1023;
      float val = acc[ct][r] + bv_;
      if (z == 0) val *= 0.125f;  // fold score scaling into q
      size_t addr = (z < 2)
          ? ((((size_t)n * HH + hh) * TT + t) * DHD + dh)     // q,k: [N,H,T,64]
          : ((((size_t)n * HH + hh) * DHD + dh) * TT + t);    // v : [N,H,64,T]
      out[addr] = f2bf(val);
    }
  }
}

// ---------------- output projection GEMM ----------------
__global__ __launch_bounds__(256) void kt_outproj(
    const short* __restrict__ A, const short* __restrict__ WT,
    const float* __restrict__ bias, float* __restrict__ out)
{
  __shared__ alignas(16) short As[64][40];
  __shared__ alignas(16) short Bs[64][40];
  int tid = threadIdx.x;
  int w = tid >> 6, lane = tid & 63, g = lane >> 4, c16 = lane & 15;
  int m0 = blockIdx.x * 64, c0 = blockIdx.y * 64;
  int srow = tid >> 2, skg = (tid & 3) * 8;
  f32x4 acc[4] = {};

  for (int kk = 0; kk < DD; kk += 32) {
    *(bf16x8*)&As[srow][skg] = *(const bf16x8*)(A + (size_t)(m0 + srow) * DD + kk + skg);
    *(bf16x8*)&Bs[srow][skg] = *(const bf16x8*)(WT + (size_t)(c0 + srow) * DD + kk + skg);
    __syncthreads();
    bf16x8 af = *(const bf16x8*)&As[w * 16 + c16][g * 8];
#pragma unroll
    for (int ct = 0; ct < 4; ++ct) {
      bf16x8 bfv = *(const bf16x8*)&Bs[ct * 16 + c16][g * 8];
      acc[ct] = MFMA(af, bfv, acc[ct]);
    }
    __syncthreads();
  }

#pragma unroll
  for (int ct = 0; ct < 4; ++ct) {
    int c = c0 + ct * 16 + c16;
    float bv_ = bias[c];
#pragma unroll
    for (int r = 0; r < 4; ++r) {
      int m = m0 + w * 16 + g * 4 + r;
      out[(size_t)m * DD + c] = acc[ct][r] + bv_;
    }
  }
}

// ---------------- fused attention, v8 ----------------
// 32 q-rows per block (256 blocks, 1/CU). 8 waves x 128-k slice; each wave
// processes TWO 16-row q-subtiles, reusing each K/V fragment twice.
// Phase-instances per CU halve (16 -> 8) and K/V load count halves, attacking
// the fixed per-phase serial cost (v1 vs v5 showed time is independent of
// per-wave load count). Same verified softmax/combine/PV math as v5-v7.
__global__ __launch_bounds__(512, 1) void kt_attn(
    const short* __restrict__ qbuf, const short* __restrict__ kbuf, const short* __restrict__ vT,
    const float* __restrict__ segms, const int* __restrict__ mask,
    short* __restrict__ attn, float* __restrict__ pmean)
{
  int bx = blockIdx.x;
  int n = bx & 7, qt = bx >> 3;          // qt 0..31; XCD-local batch
  int q0 = qt * 32;
  int tid = threadIdx.x, w = tid >> 6, lane = tid & 63, g = lane >> 4, c16 = lane & 15;
  int kw = w * 128;

  // per-wave union region: pbuf short[2][16][136] (8704 B) | outw float[2][16][66] (8448 B)
  __shared__ alignas(16) char uni[8][8704];
  __shared__ alignas(16) float red_mT[32][8];
  __shared__ alignas(16) float red_sT[32][8];
  short (*pbuf)[16][136] = (short (*)[16][136])uni[w];
  float (*outw)[16][66]  = (float (*)[16][66])uni[w];

  // ---- hoist mask bits + segms (fp16 packed); h-invariant; vectorized ----
  // lane owns q-rows (q0 + s*16 + c16), k-cols kw + ct*16 + g*4 + {0..3}
  unsigned mmv[2];
  __half2 sgp[2][8][2];
  float pm[2][8][4];
  uint32_t rowbase[2];
#pragma unroll
  for (int s = 0; s < 2; ++s) {
    rowbase[s] = ((uint32_t)(n * TT) + q0 + s * 16 + c16) * TT + kw + g * 4;
    unsigned mm = 0u;
#pragma unroll
    for (int ct = 0; ct < 8; ++ct) {
      int4   mv = *(const int4*)  &mask [rowbase[s] + ct * 16];
      float4 sg = *(const float4*)&segms[rowbase[s] + ct * 16];
      if (mv.x) mm |= 1u << (ct * 4 + 0);
      if (mv.y) mm |= 1u << (ct * 4 + 1);
      if (mv.z) mm |= 1u << (ct * 4 + 2);
      if (mv.w) mm |= 1u << (ct * 4 + 3);
      sgp[s][ct][0] = __floats2half2_rn(sg.x, sg.y);
      sgp[s][ct][1] = __floats2half2_rn(sg.z, sg.w);
      pm[s][ct][0] = 0.f; pm[s][ct][1] = 0.f; pm[s][ct][2] = 0.f; pm[s][ct][3] = 0.f;
    }
    mmv[s] = mm;
  }

  for (int hh = 0; hh < HH; ++hh) {
    int h = (hh + qt) & 7;  // stagger heads across blocks
    const short* qp = qbuf + (((size_t)n * HH + h) * TT + q0) * DHD;
    const short* kp = kbuf + (((size_t)n * HH + h) * TT) * DHD;
    const short* vp = vT   + (((size_t)n * HH + h) * DHD) * TT;

    bf16x8 aqA0 = *(const bf16x8*)(qp + c16 * DHD + g * 8);
    bf16x8 aqA1 = *(const bf16x8*)(qp + c16 * DHD + g * 8 + 32);
    bf16x8 aqB0 = *(const bf16x8*)(qp + (16 + c16) * DHD + g * 8);
    bf16x8 aqB1 = *(const bf16x8*)(qp + (16 + c16) * DHD + g * 8 + 32);

    // ---- swapped QK^T, both subtiles share each K fragment ----
    f32x4 scA[8], scB[8];
    __builtin_amdgcn_s_setprio(1);
#pragma unroll
    for (int ct = 0; ct < 8; ++ct) {
      const short* kpp = kp + (size_t)(kw + ct * 16 + c16) * DHD + g * 8;
      bf16x8 k0 = *(const bf16x8*)kpp;
      bf16x8 k1 = *(const bf16x8*)(kpp + 32);
      f32x4 a = {};
      a = MFMA(k0, aqA0, a);
      a = MFMA(k1, aqA1, a);
      scA[ct] = a;
      f32x4 b = {};
      b = MFMA(k0, aqB0, b);
      b = MFMA(k1, aqB1, b);
      scB[ct] = b;
    }
    __builtin_amdgcn_s_setprio(0);

    // ---- mask + in-lane row max + 2 shuffles (both subtiles) ----
    float mxA = -3e38f, mxB = -3e38f;
#pragma unroll
    for (int ct = 0; ct < 8; ++ct)
#pragma unroll
      for (int r = 0; r < 4; ++r) {
        float sa = ((mmv[0] >> (ct * 4 + r)) & 1u) ? scA[ct][r] : -1e9f;
        float sb = ((mmv[1] >> (ct * 4 + r)) & 1u) ? scB[ct][r] : -1e9f;
        scA[ct][r] = sa; scB[ct][r] = sb;
        mxA = fmaxf(mxA, sa); mxB = fmaxf(mxB, sb);
      }
    mxA = fmaxf(mxA, __shfl_xor(mxA, 16));
    mxA = fmaxf(mxA, __shfl_xor(mxA, 32));
    mxB = fmaxf(mxB, __shfl_xor(mxB, 16));
    mxB = fmaxf(mxB, __shfl_xor(mxB, 32));

    // ---- exp with wave-local max (p<=1 safe) + in-lane sum + 2 shuffles ----
    float smA = 0.f, smB = 0.f;
#pragma unroll
    for (int ct = 0; ct < 8; ++ct)
#pragma unroll
      for (int r = 0; r < 4; ++r) {
        float pa = __expf(scA[ct][r] - mxA);
        float pb = __expf(scB[ct][r] - mxB);
        scA[ct][r] = pa; scB[ct][r] = pb;
        smA += pa; smB += pb;
      }
    smA += __shfl_xor(smA, 16);
    smA += __shfl_xor(smA, 32);
    smB += __shfl_xor(smB, 16);
    smB += __shfl_xor(smB, 32);
    if (lane < 16) {
      red_mT[c16][w] = mxA;      red_sT[c16][w] = smA;
      red_mT[16 + c16][w] = mxB; red_sT[16 + c16][w] = smB;
    }
    __syncthreads();  // barrier A: (m,S) ready; fences prev head's outw reads vs pbuf writes

    // ---- combine for q=c16 (A) and q=16+c16 (B) ----
    float sclA, sclB;
    {
      f32x4 vm0 = *(const f32x4*)&red_mT[c16][0];
      f32x4 vm1 = *(const f32x4*)&red_mT[c16][4];
      f32x4 vs0 = *(const f32x4*)&red_sT[c16][0];
      f32x4 vs1 = *(const f32x4*)&red_sT[c16][4];
      float ms = fmaxf(fmaxf(fmaxf(vm0[0], vm0[1]), fmaxf(vm0[2], vm0[3])),
                       fmaxf(fmaxf(vm1[0], vm1[1]), fmaxf(vm1[2], vm1[3])));
      float Z = vs0[0] * __expf(vm0[0] - ms) + vs0[1] * __expf(vm0[1] - ms)
              + vs0[2] * __expf(vm0[2] - ms) + vs0[3] * __expf(vm0[3] - ms)
              + vs1[0] * __expf(vm1[0] - ms) + vs1[1] * __expf(vm1[1] - ms)
              + vs1[2] * __expf(vm1[2] - ms) + vs1[3] * __expf(vm1[3] - ms);
      sclA = __expf(mxA - ms) / Z;
    }
    {
      f32x4 vm0 = *(const f32x4*)&red_mT[16 + c16][0];
      f32x4 vm1 = *(const f32x4*)&red_mT[16 + c16][4];
      f32x4 vs0 = *(const f32x4*)&red_sT[16 + c16][0];
      f32x4 vs1 = *(const f32x4*)&red_sT[16 + c16][4];
      float ms = fmaxf(fmaxf(fmaxf(vm0[0], vm0[1]), fmaxf(vm0[2], vm0[3])),
                       fmaxf(fmaxf(vm1[0], vm1[1]), fmaxf(vm1[2], vm1[3])));
      float Z = vs0[0] * __expf(vm0[0] - ms) + vs0[1] * __expf(vm0[1] - ms)
              + vs0[2] * __expf(vm0[2] - ms) + vs0[3] * __expf(vm0[3] - ms)
              + vs1[0] * __expf(vm1[0] - ms) + vs1[1] * __expf(vm1[1] - ms)
              + vs1[2] * __expf(vm1[2] - ms) + vs1[3] * __expf(vm1[3] - ms);
      sclB = __expf(mxB - ms) / Z;
    }

    // ---- probs = p*scale*segms ; accumulate pmean ; stash packed b64 ----
#pragma unroll
    for (int ct = 0; ct < 8; ++ct) {
      {
        float2 s01 = __half22float2(sgp[0][ct][0]);
        float2 s23 = __half22float2(sgp[0][ct][1]);
        float p0 = scA[ct][0] * sclA * s01.x;
        float p1 = scA[ct][1] * sclA * s01.y;
        float p2 = scA[ct][2] * sclA * s23.x;
        float p3 = scA[ct][3] * sclA * s23.y;
        pm[0][ct][0] += p0; pm[0][ct][1] += p1; pm[0][ct][2] += p2; pm[0][ct][3] += p3;
        uint2 pk; pk.x = pkbf(p0, p1); pk.y = pkbf(p2, p3);
        *(uint2*)&pbuf[0][c16][ct * 16 + g * 4] = pk;
      }
      {
        float2 s01 = __half22float2(sgp[1][ct][0]);
        float2 s23 = __half22float2(sgp[1][ct][1]);
        float p0 = scB[ct][0] * sclB * s01.x;
        float p1 = scB[ct][1] * sclB * s01.y;
        float p2 = scB[ct][2] * sclB * s23.x;
        float p3 = scB[ct][3] * sclB * s23.y;
        pm[1][ct][0] += p0; pm[1][ct][1] += p1; pm[1][ct][2] += p2; pm[1][ct][3] += p3;
        uint2 pk; pk.x = pkbf(p0, p1); pk.y = pkbf(p2, p3);
        *(uint2*)&pbuf[1][c16][ct * 16 + g * 4] = pk;
      }
    }
    // no barrier: pbuf slice is wave-private (same-wave ds ordering)

    // ---- PV subtile A (V loads shared with B via L1) ----
    {
      f32x4 oa[4] = {};
      __builtin_amdgcn_s_setprio(1);
#pragma unroll
      for (int ks = 0; ks < 4; ++ks) {
        bf16x8 pa = *(const bf16x8*)&pbuf[0][c16][ks * 32 + g * 8];
#pragma unroll
        for (int ct = 0; ct < 4; ++ct) {
          const short* vpp = vp + (size_t)(ct * 16 + c16) * TT + kw + ks * 32 + g * 8;
          oa[ct] = MFMA(pa, *(const bf16x8*)vpp, oa[ct]);
        }
      }
      __builtin_amdgcn_s_setprio(0);
      // outw[0] spans bytes [0,4224) -> only overlaps dead pbuf[0]
#pragma unroll
      for (int ct = 0; ct < 4; ++ct)
#pragma unroll
        for (int r = 0; r < 4; ++r)
          outw[0][g * 4 + r][ct * 16 + c16] = oa[ct][r];
    }
    // ---- PV subtile B ----
    {
      f32x4 ob[4] = {};
      __builtin_amdgcn_s_setprio(1);
#pragma unroll
      for (int ks = 0; ks < 4; ++ks) {
        bf16x8 pa = *(const bf16x8*)&pbuf[1][c16][ks * 32 + g * 8];
#pragma unroll
        for (int ct = 0; ct < 4; ++ct) {
          const short* vpp = vp + (size_t)(ct * 16 + c16) * TT + kw + ks * 32 + g * 8;
          ob[ct] = MFMA(pa, *(const bf16x8*)vpp, ob[ct]);
        }
      }
      __builtin_amdgcn_s_setprio(0);
#pragma unroll
      for (int ct = 0; ct < 4; ++ct)
#pragma unroll
        for (int r = 0; r < 4; ++r)
          outw[1][g * 4 + r][ct * 16 + c16] = ob[ct][r];
    }
    __syncthreads();  // barrier C: all partials ready

    // ---- cross-wave reduce (8 partials, 32 q-rows) + write attn ----
    {
      int q = tid >> 4, dg = (tid & 15) * 4;
      int s = q >> 4, qr = q & 15;
      float v0 = 0.f, v1 = 0.f, v2 = 0.f, v3 = 0.f;
#pragma unroll
      for (int wi = 0; wi < 8; ++wi) {
        const float* op = (const float*)uni[wi] + (size_t)s * 16 * 66 + qr * 66 + dg;
        float4 rd = *(const float4*)op;
        v0 += rd.x; v1 += rd.y; v2 += rd.z; v3 += rd.w;
      }
      s16x4 st;
      st[0] = f2bf(v0); st[1] = f2bf(v1); st[2] = f2bf(v2); st[3] = f2bf(v3);
      *(s16x4*)(attn + ((size_t)(n * TT) + q0 + q) * DD + h * DHD + dg) = st;
    }
    // next head's pbuf writes are fenced by barrier A of that head
  }

  // ---- write probs mean (1/H), vectorized float4 ----
#pragma unroll
  for (int s = 0; s < 2; ++s)
#pragma unroll
    for (int ct = 0; ct < 8; ++ct) {
      float4 o;
      o.x = pm[s][ct][0] * 0.125f; o.y = pm[s][ct][1] * 0.125f;
      o.z = pm[s][ct][2] * 0.125f; o.w = pm[s][ct][3] * 0.125f;
      *(float4*)&pmean[rowbase[s] + ct * 16] = o;
    }
}

extern "C" void kernel_launch(void* const* d_in, const int* in_sizes, int n_in,
                              void* d_out, int out_size, void* d_ws, size_t ws_size,
                              hipStream_t stream) {
  const float* query = (const float*)d_in[0];
  const float* key_  = (const float*)d_in[1];
  const float* value = (const float*)d_in[2];
  const float* segms = (const float*)d_in[3];
  const int*   mask  = (const int*)d_in[4];
  const float* Wq = (const float*)d_in[5];
  const float* bq = (const float*)d_in[6];
  const float* Wk = (const float*)d_in[7];
  const float* bk = (const float*)d_in[8];
  const float* Wv = (const float*)d_in[9];
  const float* bv = (const float*)d_in[10];
  const float* Wo = (const float*)d_in[11];
  const float* bo = (const float*)d_in[12];

  char* ws = (char*)d_ws;
  short* WT   = (short*)(ws);                        // 4 x 512x512 bf16 = 2 MB
  short* qb   = (short*)(ws + ((size_t)2  << 20));   // [N,H,T,64] bf16 = 8 MB
  short* kb   = (short*)(ws + ((size_t)10 << 20));   // [N,H,T,64] bf16 = 8 MB
  short* vT   = (short*)(ws + ((size_t)18 << 20));   // [N,H,64,T] bf16 = 8 MB
  short* attn = (short*)(ws + ((size_t)26 << 20));   // [N,T,D]   bf16 = 8 MB
  float* outp  = (float*)d_out;
  float* pmean = outp + (size_t)NB * TT * DD;

  kt_transpose<<<dim3(16, 16, 4), dim3(32, 8), 0, stream>>>(Wq, Wk, Wv, Wo, WT);
  kt_proj<<<dim3(128, 8, 3), 256, 0, stream>>>(query, key_, value, WT, bq, bk, bv, qb, kb, vT);
  kt_attn<<<dim3(256), dim3(512), 0, stream>>>(qb, kb, vT, segms, mask, attn, pmean);
  kt_outproj<<<dim3(128, 8), 256, 0, stream>>>(attn, WT + (size_t)3 * DD * DD, bo, outp);
}

// Round 8
// 185.350 us; speedup vs baseline: 1.5365x; 1.0042x over previous
//
#include <hip/hip_runtime.h>
#include <hip/hip_bf16.h>
#include <hip/hip_fp16.h>
#include <cstdint>
#include <cstddef>

#define NB 8
#define TT 1024
#define DD 512
#define HH 8
#define DHD 64

using bf16x8 = __attribute__((ext_vector_type(8))) short;
using f32x4  = __attribute__((ext_vector_type(4))) float;
using s16x4  = __attribute__((ext_vector_type(4))) short;

#define MFMA(a, b, c) __builtin_amdgcn_mfma_f32_16x16x32_bf16((a), (b), (c), 0, 0, 0)

__device__ __forceinline__ short f2bf(float f) {
  union { float f; uint32_t u; } x; x.f = f;
  uint32_t r = x.u + 0x7fffu + ((x.u >> 16) & 1u);
  return (short)(r >> 16);
}

// pack two floats into two bf16 (round-nearest-even) in one u32
__device__ __forceinline__ uint32_t pkbf(float a, float b) {
  union { float f; uint32_t u; } x, y; x.f = a; y.f = b;
  uint32_t ra = x.u + 0x7fffu + ((x.u >> 16) & 1u);
  uint32_t rb = y.u + 0x7fffu + ((y.u >> 16) & 1u);
  return (ra >> 16) | (rb & 0xffff0000u);
}

// ---------------- weight transpose + f32->bf16 ----------------
__global__ __launch_bounds__(256) void kt_transpose(
    const float* __restrict__ W0, const float* __restrict__ W1,
    const float* __restrict__ W2, const float* __restrict__ W3,
    short* __restrict__ WT)
{
  __shared__ float tile[32][33];
  int z = blockIdx.z;
  const float* W = (z == 0) ? W0 : (z == 1) ? W1 : (z == 2) ? W2 : W3;
  short* out = WT + (size_t)z * DD * DD;
  int tx = threadIdx.x, ty = threadIdx.y;  // (32, 8)
  int bx = blockIdx.x * 32, by = blockIdx.y * 32;
#pragma unroll
  for (int kq = 0; kq < 4; ++kq)
    tile[ty + kq * 8][tx] = W[(size_t)(by + ty + kq * 8) * DD + bx + tx];
  __syncthreads();
#pragma unroll
  for (int kq = 0; kq < 4; ++kq)
    out[(size_t)(bx + ty + kq * 8) * DD + by + tx] = f2bf(tile[tx][ty + kq * 8]);
}

// ---------------- QKV projection GEMM ----------------
// z: 0=Q (scaled by 1/8, layout [N,H,T,64]), 1=K ([N,H,T,64]), 2=V ([N,H,64,T])
// block.x -> (batch = x&7, tile = x>>3) so batch n's Q/K/V are WRITTEN by XCD n
// (linear block id % 8 == x%8): producer-consumer XCD-locality with kt_attn.
__global__ __launch_bounds__(256) void kt_proj(
    const float* __restrict__ Xq, const float* __restrict__ Xk, const float* __restrict__ Xv,
    const short* __restrict__ WTall,
    const float* __restrict__ bq, const float* __restrict__ bk, const float* __restrict__ bv,
    short* __restrict__ qb, short* __restrict__ kb, short* __restrict__ vT)
{
  int z = blockIdx.z;
  const float* X    = (z == 0) ? Xq : (z == 1) ? Xk : Xv;
  const short* WT   = WTall + (size_t)z * DD * DD;
  const float* bias = (z == 0) ? bq : (z == 1) ? bk : bv;
  short* out        = (z == 0) ? qb : (z == 1) ? kb : vT;

  __shared__ alignas(16) short As[64][40];
  __shared__ alignas(16) short Bs[64][40];
  int tid = threadIdx.x;
  int w = tid >> 6, lane = tid & 63, g = lane >> 4, c16 = lane & 15;
  int xb = blockIdx.x;
  int m0 = ((xb & 7) * 16 + (xb >> 3)) * 64;   // XCD-local batch mapping
  int c0 = blockIdx.y * 64;
  int srow = tid >> 2, skg = (tid & 3) * 8;
  f32x4 acc[4] = {};

  for (int kk = 0; kk < DD; kk += 32) {
    const float* ap = X + (size_t)(m0 + srow) * DD + kk + skg;
    float4 a0 = *(const float4*)ap;
    float4 a1 = *(const float4*)(ap + 4);
    bf16x8 av;
    av[0] = f2bf(a0.x); av[1] = f2bf(a0.y); av[2] = f2bf(a0.z); av[3] = f2bf(a0.w);
    av[4] = f2bf(a1.x); av[5] = f2bf(a1.y); av[6] = f2bf(a1.z); av[7] = f2bf(a1.w);
    *(bf16x8*)&As[srow][skg] = av;
    *(bf16x8*)&Bs[srow][skg] = *(const bf16x8*)(WT + (size_t)(c0 + srow) * DD + kk + skg);
    __syncthreads();
    bf16x8 af = *(const bf16x8*)&As[w * 16 + c16][g * 8];
#pragma unroll
    for (int ct = 0; ct < 4; ++ct) {
      bf16x8 bfv = *(const bf16x8*)&Bs[ct * 16 + c16][g * 8];
      acc[ct] = MFMA(af, bfv, acc[ct]);
    }
    __syncthreads();
  }

#pragma unroll
  for (int ct = 0; ct < 4; ++ct) {
    int c = c0 + ct * 16 + c16;
    float bv_ = bias[c];
    int hh = c >> 6, dh = c & 63;
#pragma unroll
    for (int r = 0; r < 4; ++r) {
      int m = m0 + w * 16 + g * 4 + r;
      int n = m >> 10, t = m & 1023;
      float val = acc[ct][r] + bv_;
      if (z == 0) val *= 0.125f;  // fold score scaling into q
      size_t addr = (z < 2)
          ? ((((size_t)n * HH + hh) * TT + t) * DHD + dh)     // q,k: [N,H,T,64]
          : ((((size_t)n * HH + hh) * DHD + dh) * TT + t);    // v : [N,H,64,T]
      out[addr] = f2bf(val);
    }
  }
}

// ---------------- output projection GEMM ----------------
// same XCD-local batch mapping: reads attn[n] written by XCD n.
__global__ __launch_bounds__(256) void kt_outproj(
    const short* __restrict__ A, const short* __restrict__ WT,
    const float* __restrict__ bias, float* __restrict__ out)
{
  __shared__ alignas(16) short As[64][40];
  __shared__ alignas(16) short Bs[64][40];
  int tid = threadIdx.x;
  int w = tid >> 6, lane = tid & 63, g = lane >> 4, c16 = lane & 15;
  int xb = blockIdx.x;
  int m0 = ((xb & 7) * 16 + (xb >> 3)) * 64;   // XCD-local batch mapping
  int c0 = blockIdx.y * 64;
  int srow = tid >> 2, skg = (tid & 3) * 8;
  f32x4 acc[4] = {};

  for (int kk = 0; kk < DD; kk += 32) {
    *(bf16x8*)&As[srow][skg] = *(const bf16x8*)(A + (size_t)(m0 + srow) * DD + kk + skg);
    *(bf16x8*)&Bs[srow][skg] = *(const bf16x8*)(WT + (size_t)(c0 + srow) * DD + kk + skg);
    __syncthreads();
    bf16x8 af = *(const bf16x8*)&As[w * 16 + c16][g * 8];
#pragma unroll
    for (int ct = 0; ct < 4; ++ct) {
      bf16x8 bfv = *(const bf16x8*)&Bs[ct * 16 + c16][g * 8];
      acc[ct] = MFMA(af, bfv, acc[ct]);
    }
    __syncthreads();
  }

#pragma unroll
  for (int ct = 0; ct < 4; ++ct) {
    int c = c0 + ct * 16 + c16;
    float bv_ = bias[c];
#pragma unroll
    for (int r = 0; r < 4; ++r) {
      int m = m0 + w * 16 + g * 4 + r;
      out[(size_t)m * DD + c] = acc[ct][r] + bv_;
    }
  }
}

// ---------------- fused attention, v9 ----------------
// Identical to v8 (32 q-rows/block, 8 waves x 128-k slice, 2 q-subtiles/wave)
// except: no head stagger (h = hh) so all 32 blocks of an XCD touch the same
// 256 KB K/V working set per phase. Combined with kt_proj's XCD-local batch
// mapping, K/V reads are served by the local XCD L2 instead of the cross-XCD
// L3 fabric (the ~4-5 TB/s ceiling that v5-v8 were pinned at).
__global__ __launch_bounds__(512, 1) void kt_attn(
    const short* __restrict__ qbuf, const short* __restrict__ kbuf, const short* __restrict__ vT,
    const float* __restrict__ segms, const int* __restrict__ mask,
    short* __restrict__ attn, float* __restrict__ pmean)
{
  int bx = blockIdx.x;
  int n = bx & 7, qt = bx >> 3;          // qt 0..31; XCD-local batch
  int q0 = qt * 32;
  int tid = threadIdx.x, w = tid >> 6, lane = tid & 63, g = lane >> 4, c16 = lane & 15;
  int kw = w * 128;

  // per-wave union region: pbuf short[2][16][136] (8704 B) | outw float[2][16][66] (8448 B)
  __shared__ alignas(16) char uni[8][8704];
  __shared__ alignas(16) float red_mT[32][8];
  __shared__ alignas(16) float red_sT[32][8];
  short (*pbuf)[16][136] = (short (*)[16][136])uni[w];
  float (*outw)[16][66]  = (float (*)[16][66])uni[w];

  // ---- hoist mask bits + segms (fp16 packed); h-invariant; vectorized ----
  unsigned mmv[2];
  __half2 sgp[2][8][2];
  float pm[2][8][4];
  uint32_t rowbase[2];
#pragma unroll
  for (int s = 0; s < 2; ++s) {
    rowbase[s] = ((uint32_t)(n * TT) + q0 + s * 16 + c16) * TT + kw + g * 4;
    unsigned mm = 0u;
#pragma unroll
    for (int ct = 0; ct < 8; ++ct) {
      int4   mv = *(const int4*)  &mask [rowbase[s] + ct * 16];
      float4 sg = *(const float4*)&segms[rowbase[s] + ct * 16];
      if (mv.x) mm |= 1u << (ct * 4 + 0);
      if (mv.y) mm |= 1u << (ct * 4 + 1);
      if (mv.z) mm |= 1u << (ct * 4 + 2);
      if (mv.w) mm |= 1u << (ct * 4 + 3);
      sgp[s][ct][0] = __floats2half2_rn(sg.x, sg.y);
      sgp[s][ct][1] = __floats2half2_rn(sg.z, sg.w);
      pm[s][ct][0] = 0.f; pm[s][ct][1] = 0.f; pm[s][ct][2] = 0.f; pm[s][ct][3] = 0.f;
    }
    mmv[s] = mm;
  }

  for (int h = 0; h < HH; ++h) {
    const short* qp = qbuf + (((size_t)n * HH + h) * TT + q0) * DHD;
    const short* kp = kbuf + (((size_t)n * HH + h) * TT) * DHD;
    const short* vp = vT   + (((size_t)n * HH + h) * DHD) * TT;

    bf16x8 aqA0 = *(const bf16x8*)(qp + c16 * DHD + g * 8);
    bf16x8 aqA1 = *(const bf16x8*)(qp + c16 * DHD + g * 8 + 32);
    bf16x8 aqB0 = *(const bf16x8*)(qp + (16 + c16) * DHD + g * 8);
    bf16x8 aqB1 = *(const bf16x8*)(qp + (16 + c16) * DHD + g * 8 + 32);

    // ---- swapped QK^T, both subtiles share each K fragment ----
    f32x4 scA[8], scB[8];
    __builtin_amdgcn_s_setprio(1);
#pragma unroll
    for (int ct = 0; ct < 8; ++ct) {
      const short* kpp = kp + (size_t)(kw + ct * 16 + c16) * DHD + g * 8;
      bf16x8 k0 = *(const bf16x8*)kpp;
      bf16x8 k1 = *(const bf16x8*)(kpp + 32);
      f32x4 a = {};
      a = MFMA(k0, aqA0, a);
      a = MFMA(k1, aqA1, a);
      scA[ct] = a;
      f32x4 b = {};
      b = MFMA(k0, aqB0, b);
      b = MFMA(k1, aqB1, b);
      scB[ct] = b;
    }
    __builtin_amdgcn_s_setprio(0);

    // ---- mask + in-lane row max + 2 shuffles (both subtiles) ----
    float mxA = -3e38f, mxB = -3e38f;
#pragma unroll
    for (int ct = 0; ct < 8; ++ct)
#pragma unroll
      for (int r = 0; r < 4; ++r) {
        float sa = ((mmv[0] >> (ct * 4 + r)) & 1u) ? scA[ct][r] : -1e9f;
        float sb = ((mmv[1] >> (ct * 4 + r)) & 1u) ? scB[ct][r] : -1e9f;
        scA[ct][r] = sa; scB[ct][r] = sb;
        mxA = fmaxf(mxA, sa); mxB = fmaxf(mxB, sb);
      }
    mxA = fmaxf(mxA, __shfl_xor(mxA, 16));
    mxA = fmaxf(mxA, __shfl_xor(mxA, 32));
    mxB = fmaxf(mxB, __shfl_xor(mxB, 16));
    mxB = fmaxf(mxB, __shfl_xor(mxB, 32));

    // ---- exp with wave-local max (p<=1 safe) + in-lane sum + 2 shuffles ----
    float smA = 0.f, smB = 0.f;
#pragma unroll
    for (int ct = 0; ct < 8; ++ct)
#pragma unroll
      for (int r = 0; r < 4; ++r) {
        float pa = __expf(scA[ct][r] - mxA);
        float pb = __expf(scB[ct][r] - mxB);
        scA[ct][r] = pa; scB[ct][r] = pb;
        smA += pa; smB += pb;
      }
    smA += __shfl_xor(smA, 16);
    smA += __shfl_xor(smA, 32);
    smB += __shfl_xor(smB, 16);
    smB += __shfl_xor(smB, 32);
    if (lane < 16) {
      red_mT[c16][w] = mxA;      red_sT[c16][w] = smA;
      red_mT[16 + c16][w] = mxB; red_sT[16 + c16][w] = smB;
    }
    __syncthreads();  // barrier A: (m,S) ready; fences prev head's outw reads vs pbuf writes

    // ---- combine for q=c16 (A) and q=16+c16 (B) ----
    float sclA, sclB;
    {
      f32x4 vm0 = *(const f32x4*)&red_mT[c16][0];
      f32x4 vm1 = *(const f32x4*)&red_mT[c16][4];
      f32x4 vs0 = *(const f32x4*)&red_sT[c16][0];
      f32x4 vs1 = *(const f32x4*)&red_sT[c16][4];
      float ms = fmaxf(fmaxf(fmaxf(vm0[0], vm0[1]), fmaxf(vm0[2], vm0[3])),
                       fmaxf(fmaxf(vm1[0], vm1[1]), fmaxf(vm1[2], vm1[3])));
      float Z = vs0[0] * __expf(vm0[0] - ms) + vs0[1] * __expf(vm0[1] - ms)
              + vs0[2] * __expf(vm0[2] - ms) + vs0[3] * __expf(vm0[3] - ms)
              + vs1[0] * __expf(vm1[0] - ms) + vs1[1] * __expf(vm1[1] - ms)
              + vs1[2] * __expf(vm1[2] - ms) + vs1[3] * __expf(vm1[3] - ms);
      sclA = __expf(mxA - ms) / Z;
    }
    {
      f32x4 vm0 = *(const f32x4*)&red_mT[16 + c16][0];
      f32x4 vm1 = *(const f32x4*)&red_mT[16 + c16][4];
      f32x4 vs0 = *(const f32x4*)&red_sT[16 + c16][0];
      f32x4 vs1 = *(const f32x4*)&red_sT[16 + c16][4];
      float ms = fmaxf(fmaxf(fmaxf(vm0[0], vm0[1]), fmaxf(vm0[2], vm0[3])),
                       fmaxf(fmaxf(vm1[0], vm1[1]), fmaxf(vm1[2], vm1[3])));
      float Z = vs0[0] * __expf(vm0[0] - ms) + vs0[1] * __expf(vm0[1] - ms)
              + vs0[2] * __expf(vm0[2] - ms) + vs0[3] * __expf(vm0[3] - ms)
              + vs1[0] * __expf(vm1[0] - ms) + vs1[1] * __expf(vm1[1] - ms)
              + vs1[2] * __expf(vm1[2] - ms) + vs1[3] * __expf(vm1[3] - ms);
      sclB = __expf(mxB - ms) / Z;
    }

    // ---- probs = p*scale*segms ; accumulate pmean ; stash packed b64 ----
#pragma unroll
    for (int ct = 0; ct < 8; ++ct) {
      {
        float2 s01 = __half22float2(sgp[0][ct][0]);
        float2 s23 = __half22float2(sgp[0][ct][1]);
        float p0 = scA[ct][0] * sclA * s01.x;
        float p1 = scA[ct][1] * sclA * s01.y;
        float p2 = scA[ct][2] * sclA * s23.x;
        float p3 = scA[ct][3] * sclA * s23.y;
        pm[0][ct][0] += p0; pm[0][ct][1] += p1; pm[0][ct][2] += p2; pm[0][ct][3] += p3;
        uint2 pk; pk.x = pkbf(p0, p1); pk.y = pkbf(p2, p3);
        *(uint2*)&pbuf[0][c16][ct * 16 + g * 4] = pk;
      }
      {
        float2 s01 = __half22float2(sgp[1][ct][0]);
        float2 s23 = __half22float2(sgp[1][ct][1]);
        float p0 = scB[ct][0] * sclB * s01.x;
        float p1 = scB[ct][1] * sclB * s01.y;
        float p2 = scB[ct][2] * sclB * s23.x;
        float p3 = scB[ct][3] * sclB * s23.y;
        pm[1][ct][0] += p0; pm[1][ct][1] += p1; pm[1][ct][2] += p2; pm[1][ct][3] += p3;
        uint2 pk; pk.x = pkbf(p0, p1); pk.y = pkbf(p2, p3);
        *(uint2*)&pbuf[1][c16][ct * 16 + g * 4] = pk;
      }
    }
    // no barrier: pbuf slice is wave-private (same-wave ds ordering)

    // ---- PV subtile A ----
    {
      f32x4 oa[4] = {};
      __builtin_amdgcn_s_setprio(1);
#pragma unroll
      for (int ks = 0; ks < 4; ++ks) {
        bf16x8 pa = *(const bf16x8*)&pbuf[0][c16][ks * 32 + g * 8];
#pragma unroll
        for (int ct = 0; ct < 4; ++ct) {
          const short* vpp = vp + (size_t)(ct * 16 + c16) * TT + kw + ks * 32 + g * 8;
          oa[ct] = MFMA(pa, *(const bf16x8*)vpp, oa[ct]);
        }
      }
      __builtin_amdgcn_s_setprio(0);
#pragma unroll
      for (int ct = 0; ct < 4; ++ct)
#pragma unroll
        for (int r = 0; r < 4; ++r)
          outw[0][g * 4 + r][ct * 16 + c16] = oa[ct][r];
    }
    // ---- PV subtile B ----
    {
      f32x4 ob[4] = {};
      __builtin_amdgcn_s_setprio(1);
#pragma unroll
      for (int ks = 0; ks < 4; ++ks) {
        bf16x8 pa = *(const bf16x8*)&pbuf[1][c16][ks * 32 + g * 8];
#pragma unroll
        for (int ct = 0; ct < 4; ++ct) {
          const short* vpp = vp + (size_t)(ct * 16 + c16) * TT + kw + ks * 32 + g * 8;
          ob[ct] = MFMA(pa, *(const bf16x8*)vpp, ob[ct]);
        }
      }
      __builtin_amdgcn_s_setprio(0);
#pragma unroll
      for (int ct = 0; ct < 4; ++ct)
#pragma unroll
        for (int r = 0; r < 4; ++r)
          outw[1][g * 4 + r][ct * 16 + c16] = ob[ct][r];
    }
    __syncthreads();  // barrier C: all partials ready

    // ---- cross-wave reduce (8 partials, 32 q-rows) + write attn ----
    {
      int q = tid >> 4, dg = (tid & 15) * 4;
      int s = q >> 4, qr = q & 15;
      float v0 = 0.f, v1 = 0.f, v2 = 0.f, v3 = 0.f;
#pragma unroll
      for (int wi = 0; wi < 8; ++wi) {
        const float* op = (const float*)uni[wi] + (size_t)s * 16 * 66 + qr * 66 + dg;
        float4 rd = *(const float4*)op;
        v0 += rd.x; v1 += rd.y; v2 += rd.z; v3 += rd.w;
      }
      s16x4 st;
      st[0] = f2bf(v0); st[1] = f2bf(v1); st[2] = f2bf(v2); st[3] = f2bf(v3);
      *(s16x4*)(attn + ((size_t)(n * TT) + q0 + q) * DD + h * DHD + dg) = st;
    }
    // next head's pbuf writes are fenced by barrier A of that head
  }

  // ---- write probs mean (1/H), vectorized float4 ----
#pragma unroll
  for (int s = 0; s < 2; ++s)
#pragma unroll
    for (int ct = 0; ct < 8; ++ct) {
      float4 o;
      o.x = pm[s][ct][0] * 0.125f; o.y = pm[s][ct][1] * 0.125f;
      o.z = pm[s][ct][2] * 0.125f; o.w = pm[s][ct][3] * 0.125f;
      *(float4*)&pmean[rowbase[s] + ct * 16] = o;
    }
}

extern "C" void kernel_launch(void* const* d_in, const int* in_sizes, int n_in,
                              void* d_out, int out_size, void* d_ws, size_t ws_size,
                              hipStream_t stream) {
  const float* query = (const float*)d_in[0];
  const float* key_  = (const float*)d_in[1];
  const float* value = (const float*)d_in[2];
  const float* segms = (const float*)d_in[3];
  const int*   mask  = (const int*)d_in[4];
  const float* Wq = (const float*)d_in[5];
  const float* bq = (const float*)d_in[6];
  const float* Wk = (const float*)d_in[7];
  const float* bk = (const float*)d_in[8];
  const float* Wv = (const float*)d_in[9];
  const float* bv = (const float*)d_in[10];
  const float* Wo = (const float*)d_in[11];
  const float* bo = (const float*)d_in[12];

  char* ws = (char*)d_ws;
  short* WT   = (short*)(ws);                        // 4 x 512x512 bf16 = 2 MB
  short* qb   = (short*)(ws + ((size_t)2  << 20));   // [N,H,T,64] bf16 = 8 MB
  short* kb   = (short*)(ws + ((size_t)10 << 20));   // [N,H,T,64] bf16 = 8 MB
  short* vT   = (short*)(ws + ((size_t)18 << 20));   // [N,H,64,T] bf16 = 8 MB
  short* attn = (short*)(ws + ((size_t)26 << 20));   // [N,T,D]   bf16 = 8 MB
  float* outp  = (float*)d_out;
  float* pmean = outp + (size_t)NB * TT * DD;

  kt_transpose<<<dim3(16, 16, 4), dim3(32, 8), 0, stream>>>(Wq, Wk, Wv, Wo, WT);
  kt_proj<<<dim3(128, 8, 3), 256, 0, stream>>>(query, key_, value, WT, bq, bk, bv, qb, kb, vT);
  kt_attn<<<dim3(256), dim3(512), 0, stream>>>(qb, kb, vT, segms, mask, attn, pmean);
  kt_outproj<<<dim3(128, 8), 256, 0, stream>>>(attn, WT + (size_t)3 * DD * DD, bo, outp);
}